// Round 10
// baseline (802.907 us; speedup 1.0000x reference)
//
#include <hip/hip_runtime.h>
#include <math.h>

#define NNODES 262144      // B*N
#define NEDGE  2097152     // NNODES*DEG
#define NB     256         // graphs
#define NPG    1024        // nodes per graph
#define EPG    8192        // edges per graph
#define DF     128         // feature dim

typedef unsigned short u16;
typedef unsigned int   u32;
typedef unsigned long long u64;
typedef __attribute__((ext_vector_type(8))) short  short8;   // 8 x bf16 (4 VGPRs)
typedef __attribute__((ext_vector_type(4))) float  floatx4;  // MFMA accumulator

static constexpr int K1 = 820, K2 = 656, K3 = 525;

// ---- bf16 helpers (manual, RTNE) ----
__device__ inline float bflo(u32 u) { union { u32 i; float f; } c; c.i = u << 16;          return c.f; }
__device__ inline float bfhi(u32 u) { union { u32 i; float f; } c; c.i = u & 0xffff0000u;  return c.f; }
__device__ inline u32   f2bf(float f) {
  union { float f; u32 i; } c; c.f = f;
  const u32 r = c.i + 0x7fffu + ((c.i >> 16) & 1u);
  return r >> 16;
}
__device__ inline void acc8(float* b, uint4 v) {
  b[0] += bflo(v.x); b[1] += bfhi(v.x);
  b[2] += bflo(v.y); b[3] += bfhi(v.y);
  b[4] += bflo(v.z); b[5] += bfhi(v.z);
  b[6] += bflo(v.w); b[7] += bfhi(v.w);
}
__device__ inline uint4 pack8(const float* s, float k) {
  uint4 o;
  o.x = f2bf(s[0] * k) | (f2bf(s[1] * k) << 16);
  o.y = f2bf(s[2] * k) | (f2bf(s[3] * k) << 16);
  o.z = f2bf(s[4] * k) | (f2bf(s[5] * k) << 16);
  o.w = f2bf(s[6] * k) | (f2bf(s[7] * k) << 16);
  return o;
}

// ---------------- CSR build (1024 thr): counting sort by dst + deg/keep init ----
__global__ __launch_bounds__(1024) void build_csr_k(
    const int* __restrict__ ei, int* __restrict__ csr_src,
    int* __restrict__ row_off, int* __restrict__ row_cnt,
    float* __restrict__ degf, float* __restrict__ keep,
    int* __restrict__ perm)
{
  __shared__ int cnt[NPG];
  __shared__ int roff[NPG];
  __shared__ int wsum[NPG];
  __shared__ int hist[64];
  __shared__ int hoff[64];
  const int b = blockIdx.x, t = threadIdx.x;   // t in 0..1023
  const int* src = ei;
  const int* dst = ei + NEDGE;
  const int e0 = b * EPG;
  cnt[t] = 0;
  __syncthreads();
  for (int e = t; e < EPG; e += 1024) atomicAdd(&cnt[dst[e0 + e] & (NPG - 1)], 1);
  __syncthreads();
  const int v = cnt[t];
  wsum[t] = v;
  __syncthreads();
  for (int off = 1; off < NPG; off <<= 1) {
    const int u = (t >= off) ? wsum[t - off] : 0;
    __syncthreads();
    wsum[t] += u;
    __syncthreads();
  }
  const int base = wsum[t] - v;    // exclusive prefix
  roff[t] = base;
  const int n = b * NPG + t;
  row_off[n] = base;
  row_cnt[n] = v;
  degf[n]    = (float)v;           // layer-1 deg = full in-degree
  keep[n]    = 1.0f;
  if (t < 64) hist[t] = 0;
  __syncthreads();
  for (int e = t; e < EPG; e += 1024) {
    const int dl = dst[e0 + e] & (NPG - 1);
    const int pos = atomicAdd(&roff[dl], 1);
    csr_src[e0 + pos] = src[e0 + e];   // store GLOBAL src node id
  }
  // ---- degree-sorted permutation (counting sort over clamped degree) ----
  const int bkt = (v < 63) ? v : 63;
  atomicAdd(&hist[bkt], 1);
  __syncthreads();
  if (t == 0) {
    int s = 0;
#pragma unroll 1
    for (int i = 0; i < 64; ++i) { const int h = hist[i]; hoff[i] = s; s += h; }
  }
  __syncthreads();
  const int pp = atomicAdd(&hoff[bkt], 1);
  perm[b * NPG + pp] = t;
}

// ---------------- Embedding gather (f32 -> bf16, unscaled) + fac init -----------
__global__ __launch_bounds__(256) void gather_k(
    const int* __restrict__ x_ids, const float* __restrict__ emb,
    u16* __restrict__ x0, float* __restrict__ fac)
{
  const int gid = blockIdx.x * 256 + threadIdx.x;  // NNODES*16 threads
  const int n = gid >> 4, c = gid & 15;
  const int id = x_ids[n];
  const float4 v0 = *(const float4*)(emb + (size_t)id * DF + c * 8);
  const float4 v1 = *(const float4*)(emb + (size_t)id * DF + c * 8 + 4);
  uint4 pk;
  pk.x = f2bf(v0.x) | (f2bf(v0.y) << 16);
  pk.y = f2bf(v0.z) | (f2bf(v0.w) << 16);
  pk.z = f2bf(v1.x) | (f2bf(v1.y) << 16);
  pk.w = f2bf(v1.z) | (f2bf(v1.w) << 16);
  *(uint4*)(x0 + (size_t)n * DF + c * 8) = pk;
  if (c == 0) fac[n] = 1.0f;
}

// ---- Weight convert into SWIZZLED fragment order -------------------------------
__global__ __launch_bounds__(64) void wcvt_k(
    const float* __restrict__ Wl1, const float* __restrict__ Wr1,
    const float* __restrict__ Wl2, const float* __restrict__ Wr2,
    const float* __restrict__ Wl3, const float* __restrict__ Wr3,
    u16* __restrict__ wF)
{
  const int f = blockIdx.x & 63, l = blockIdx.x >> 6;
  const int lane = threadIdx.x;
  const int ct = f >> 3, ks = f & 7;
  const int n = ct * 16 + (lane & 15);
  const int k0 = ks * 32 + (lane >> 4) * 8;
  const float* Wl = (l == 0) ? Wl1 : (l == 1) ? Wl2 : Wl3;
  const float* Wr = (l == 0) ? Wr1 : (l == 1) ? Wr2 : Wr3;
  u16 o[8];
#pragma unroll
  for (int j = 0; j < 8; ++j) {
    const int k = k0 + j;
    const float v = (k < 128) ? Wl[k * 128 + n] : Wr[(k - 128) * 128 + n];
    o[j] = (u16)f2bf(v);
  }
  uint4 pk;
  pk.x = (u32)o[0] | ((u32)o[1] << 16);
  pk.y = (u32)o[2] | ((u32)o[3] << 16);
  pk.z = (u32)o[4] | ((u32)o[5] << 16);
  pk.w = (u32)o[6] | ((u32)o[7] << 16);
  *(uint4*)(wF + (((size_t)l * 64 + f) * 64 + lane) * 8) = pk;
}

// ---- Aggregation v10: clean structure + 8-group swizzle ------------------------
__global__ __launch_bounds__(1024) void agg_k(
    const u16* __restrict__ xprev, const float* __restrict__ fac,
    const float* __restrict__ deg,
    const int* __restrict__ csr_src, const int* __restrict__ row_off,
    const int* __restrict__ row_cnt, const int* __restrict__ perm,
    u16* __restrict__ aggb)
{
  __shared__ u32 xl[16384];          // 64 KB: 1024 rows x 16 dwords (32 bf16)
  const int t = threadIdx.x;
  const int bi = blockIdx.x;         // 1024 = 256 graphs x 4 quarters
  const int g  = (bi & 7) + 8 * (bi >> 5);     // XCD swizzle
  const int qt = (bi >> 3) & 3;
  const int n  = g * NPG + t;
  // ---- stage (scaled; 8-group swizzle: group = 4*(r&1) + ((r>>1)&3)) ----
  {
    const float fr = fac[n];
    const uint4* src = (const uint4*)(xprev + (size_t)n * DF + qt * 32);
    u32* dst = xl + t * 16;
    const int sw = ((t >> 1) & 3) << 2;
#pragma unroll
    for (int j = 0; j < 4; ++j) {
      const uint4 v = src[j];
      uint4 o;
      o.x = f2bf(bflo(v.x) * fr) | (f2bf(bfhi(v.x) * fr) << 16);
      o.y = f2bf(bflo(v.y) * fr) | (f2bf(bfhi(v.y) * fr) << 16);
      o.z = f2bf(bflo(v.z) * fr) | (f2bf(bfhi(v.z) * fr) << 16);
      o.w = f2bf(bflo(v.w) * fr) | (f2bf(bfhi(v.w) * fr) << 16);
      *(uint4*)(dst + ((j << 2) ^ sw)) = o;
    }
  }
  const int m  = perm[n];            // node this thread aggregates
  const int nm = g * NPG + m;
  __syncthreads();
  // ---- gather-sum from LDS (pairwise) ----
  const int cnt = row_cnt[nm];
  const int* ep = csr_src + g * EPG + row_off[nm];
  float b[32];
#pragma unroll
  for (int j = 0; j < 32; ++j) b[j] = 0.0f;
  int e = 0;
  for (; e + 2 <= cnt; e += 2) {
    const int s0 = ep[e] & (NPG - 1), s1 = ep[e + 1] & (NPG - 1);
    const u32* r0 = xl + s0 * 16; const int w0 = ((s0 >> 1) & 3) << 2;
    const u32* r1 = xl + s1 * 16; const int w1 = ((s1 >> 1) & 3) << 2;
    const uint4 A0 = *(const uint4*)(r0 + (0  ^ w0));
    const uint4 A1 = *(const uint4*)(r0 + (4  ^ w0));
    const uint4 A2 = *(const uint4*)(r0 + (8  ^ w0));
    const uint4 A3 = *(const uint4*)(r0 + (12 ^ w0));
    const uint4 B0 = *(const uint4*)(r1 + (0  ^ w1));
    const uint4 B1 = *(const uint4*)(r1 + (4  ^ w1));
    const uint4 B2 = *(const uint4*)(r1 + (8  ^ w1));
    const uint4 B3 = *(const uint4*)(r1 + (12 ^ w1));
    acc8(b + 0, A0); acc8(b + 8, A1); acc8(b + 16, A2); acc8(b + 24, A3);
    acc8(b + 0, B0); acc8(b + 8, B1); acc8(b + 16, B2); acc8(b + 24, B3);
  }
  if (e < cnt) {
    const int s0 = ep[e] & (NPG - 1);
    const u32* r0 = xl + s0 * 16; const int w0 = ((s0 >> 1) & 3) << 2;
    const uint4 A0 = *(const uint4*)(r0 + (0  ^ w0));
    const uint4 A1 = *(const uint4*)(r0 + (4  ^ w0));
    const uint4 A2 = *(const uint4*)(r0 + (8  ^ w0));
    const uint4 A3 = *(const uint4*)(r0 + (12 ^ w0));
    acc8(b + 0, A0); acc8(b + 8, A1); acc8(b + 16, A2); acc8(b + 24, A3);
  }
  const float inv = 1.0f / fmaxf(deg[nm], 1.0f);
  uint4* op = (uint4*)(aggb + (size_t)nm * DF + qt * 32);
  op[0] = pack8(b + 0,  inv);
  op[1] = pack8(b + 8,  inv);
  op[2] = pack8(b + 16, inv);
  op[3] = pack8(b + 24, inv);
}

// ---- MFMA GEMM v6: weights in LDS (frees 128 VGPRs), barrier-free main loop ----
__global__ __launch_bounds__(512) void gemm_nb_k(
    const u16* __restrict__ G, const u16* __restrict__ F,
    const float* __restrict__ fac,
    const u16* __restrict__ wF, const float* __restrict__ bl,
    const float* __restrict__ p, u16* __restrict__ H,
    float* __restrict__ score)
{
  __shared__ uint4 wL[4096];           // 64 KB: fragment (f,lane) -> uint4
  __shared__ float sc[256][2];
  const int t = threadIdx.x;
  const int bi = blockIdx.x;           // 1024 = 256 graphs x 4
  const int g   = (bi & 7) + 8 * (bi >> 5);
  const int tpg = (bi >> 3) & 3;
  const int n0  = g * NPG + tpg * 256;
  const int wv = t >> 6, lane = t & 63;
  const int rg = wv >> 1, ch = wv & 1;
  const int lr = lane & 15, quad = lane >> 4;

  // ---- stage layer weights into LDS (once per block) ----
  {
    const uint4* ws = (const uint4*)wF;
#pragma unroll
    for (int c = 0; c < 8; ++c) wL[t + c * 512] = ws[t + c * 512];
  }
  float4 bn4[4], pn4[4];
#pragma unroll
  for (int ct = 0; ct < 4; ++ct) {
    const int fb = ch * 64 + ct * 16 + quad * 4;
    bn4[ct] = *(const float4*)(bl + fb);
    pn4[ct] = *(const float4*)(p + fb);
  }

  const int rb0 = n0 + rg * 64 + lr;
  short8 agc[4], axc[4], agn[4], axn[4];
  float frc, frn = 0.0f;
#pragma unroll
  for (int ks = 0; ks < 4; ++ks) {
    agn[ks] = (short8)(short)0;
    axn[ks] = (short8)(short)0;
    agc[ks] = *(const short8*)(G + (size_t)rb0 * DF + ks * 32 + quad * 8);
    axc[ks] = *(const short8*)(F + (size_t)rb0 * DF + ks * 32 + quad * 8);
  }
  frc = fac[rb0];
  __syncthreads();                     // weights staged

  const short8* wLs = (const short8*)wL;   // fragment f at wLs[f*64+lane]
#pragma unroll
  for (int tl = 0; tl < 4; ++tl) {
    const int row = rb0 + tl * 16;
    if (tl < 3) {
      const int rown = row + 16;
#pragma unroll
      for (int ks = 0; ks < 4; ++ks) {
        agn[ks] = *(const short8*)(G + (size_t)rown * DF + ks * 32 + quad * 8);
        axn[ks] = *(const short8*)(F + (size_t)rown * DF + ks * 32 + quad * 8);
      }
      frn = fac[rown];
    }
    floatx4 aL[4], aR[4];
#pragma unroll
    for (int ct = 0; ct < 4; ++ct) {
      aL[ct] = (floatx4){0.f, 0.f, 0.f, 0.f};
      aR[ct] = (floatx4){0.f, 0.f, 0.f, 0.f};
    }
#pragma unroll
    for (int ks = 0; ks < 4; ++ks)
#pragma unroll
      for (int ct = 0; ct < 4; ++ct) {
        const int f = (ch * 4 + ct) * 8;
        const short8 bfa = wLs[(size_t)(f + ks) * 64 + lane];
        const short8 bfb = wLs[(size_t)(f + ks + 4) * 64 + lane];
        aL[ct] = __builtin_amdgcn_mfma_f32_16x16x32_bf16(bfa, agc[ks], aL[ct], 0, 0, 0);
        aR[ct] = __builtin_amdgcn_mfma_f32_16x16x32_bf16(bfb, axc[ks], aR[ct], 0, 0, 0);
      }
    float si = 0.0f;
#pragma unroll
    for (int ct = 0; ct < 4; ++ct) {
      float v0 = fmaxf(aL[ct][0] + frc * aR[ct][0] + bn4[ct].x, 0.0f);
      float v1 = fmaxf(aL[ct][1] + frc * aR[ct][1] + bn4[ct].y, 0.0f);
      float v2 = fmaxf(aL[ct][2] + frc * aR[ct][2] + bn4[ct].z, 0.0f);
      float v3 = fmaxf(aL[ct][3] + frc * aR[ct][3] + bn4[ct].w, 0.0f);
      si += v0 * pn4[ct].x + v1 * pn4[ct].y + v2 * pn4[ct].z + v3 * pn4[ct].w;
      uint2 st;
      st.x = f2bf(v0) | (f2bf(v1) << 16);
      st.y = f2bf(v2) | (f2bf(v3) << 16);
      *(uint2*)(H + (size_t)row * DF + ch * 64 + ct * 16 + quad * 4) = st;
    }
    si += __shfl_xor(si, 16, 64);
    si += __shfl_xor(si, 32, 64);
    if (lane < 16) sc[rg * 64 + tl * 16 + lr][ch] = si;
#pragma unroll
    for (int ks = 0; ks < 4; ++ks) { agc[ks] = agn[ks]; axc[ks] = axn[ks]; }
    frc = frn;
  }
  __syncthreads();   // sc complete across ch pair
  if (t < 256) score[n0 + t] = sc[t][0] + sc[t][1];
}

// ---- rank v3: O(N) radix-select (replaces the O(N^2) LDS-issue-bound scan) ----
// Map scores to order-preserving u32 (inactive -> 0), 4 byte-passes of 256-bin
// histogram find the exact K-th value u* and Kr tied slots; keep = u>u* or
// (u==u* and tie-index < Kr). Tie index via ballot + wave totals. Exactly
// reproduces stable argsort(-s) semantics (ties by smaller index first).
__global__ __launch_bounds__(1024) void rank_k(
    const float* __restrict__ score, const float* __restrict__ p,
    const int* __restrict__ ei,
    float* __restrict__ keep, float* __restrict__ fac,
    float* __restrict__ degN, int K, int next)
{
  __shared__ int hist[256];
  __shared__ int hsel[2];            // [bin, cumAbove]
  __shared__ int wtie[16];
  __shared__ float kfl[NPG];
  __shared__ float deg_l[NPG];
  const int b = blockIdx.x, t = threadIdx.x;
  float ssq = 0.0f;
  for (int d = 0; d < DF; ++d) ssq += p[d] * p[d];
  const float inv_pn = 1.0f / sqrtf(ssq);
  const int n = b * NPG + t;
  const float sc = score[n];
  const bool act = keep[n] > 0.5f;
  u32 u;
  {
    union { float f; u32 i; } c; c.f = sc;
    u = (c.i & 0x80000000u) ? ~c.i : (c.i | 0x80000000u);
    if (!act) u = 0u;                // strictly below every active mapping
  }
  deg_l[t] = 0.0f;
  // ---- 4-pass radix select for the K-th largest u ----
  u32 prefix = 0, pmask = 0;
  int Kr = K;
#pragma unroll 1
  for (int pass = 0; pass < 4; ++pass) {
    const int shift = 24 - pass * 8;
    if (t < 256) hist[t] = 0;
    __syncthreads();
    if ((u & pmask) == prefix) atomicAdd(&hist[(u >> shift) & 255], 1);
    __syncthreads();
    if (t == 0) {
      int c = 0, bsel = 0;
#pragma unroll 1
      for (int bb = 255; bb >= 0; --bb) {
        const int h = hist[bb];
        if (c + h >= Kr) { bsel = bb; break; }
        c += h;
      }
      hsel[0] = bsel; hsel[1] = c;
    }
    __syncthreads();
    prefix |= ((u32)hsel[0]) << shift;
    pmask  |= 0xFFu << shift;
    Kr     -= hsel[1];
  }
  // ---- tie index (count of tied nodes with smaller t) ----
  const int lane = t & 63, wv = t >> 6;
  const bool tie = (u == prefix);
  const u64 mb = __ballot(tie);
  const int tl = __popcll(mb & ((1ULL << lane) - 1ULL));
  if (lane == 0) wtie[wv] = (int)__popcll(mb);
  __syncthreads();
  int tsum = 0;
#pragma unroll
  for (int w = 0; w < 16; ++w) tsum += (w < wv) ? wtie[w] : 0;
  const bool kp = (u > prefix) || (tie && (tsum + tl) < Kr);
  const float fv = kp ? tanhf(sc * inv_pn) : 0.0f;
  keep[n] = kp ? 1.0f : 0.0f;
  fac[n]  = fv;
  kfl[t]  = kp ? 1.0f : 0.0f;
  __syncthreads();
  if (next) {
    const int e0 = b * EPG;
    for (int e = t; e < EPG; e += 1024) {
      const int sl = ei[e0 + e] & (NPG - 1);
      const int dl = ei[NEDGE + e0 + e] & (NPG - 1);
      atomicAdd(&deg_l[dl], kfl[sl]);
    }
    __syncthreads();
    degN[n] = deg_l[t];
  }
}

// ---- Parallel masked readout: 8 blocks/graph (standalone -- fusion into agg or
// rank measured +19/+36us vs ~11us here; 2048 blocks overlap what barrier-phased
// 1-block/CU kernels serialize) ----
__global__ __launch_bounds__(256) void readout_k(
    const u16* __restrict__ xn, const float* __restrict__ fac,
    const float* __restrict__ keep, float* __restrict__ xlp)
{
  __shared__ float mxA[256], mxB[256], smA[256], smB[256];
  const int blk = blockIdx.x, b = blk >> 3, pr = blk & 7, t = threadIdx.x;
  const int d = t & 63, rq = t >> 6;
  const float NEG = -__builtin_huge_valf();
  float mx0 = NEG, mx1 = NEG, sm0 = 0.0f, sm1 = 0.0f;
  for (int j = 0; j < 32; ++j) {
    const int n = b * NPG + pr * 128 + rq + j * 4;
    const float kf = keep[n];
    const float f  = fac[n];
    const u32 u = *(const u32*)(xn + (size_t)n * DF + d * 2);
    const float v0 = bflo(u) * f, v1 = bfhi(u) * f;
    if (kf > 0.5f) {
      mx0 = fmaxf(mx0, v0); mx1 = fmaxf(mx1, v1);
      sm0 += v0; sm1 += v1;
    }
  }
  mxA[t] = mx0; mxB[t] = mx1; smA[t] = sm0; smB[t] = sm1;
  __syncthreads();
  if (t < 64) {
    float m0 = mxA[t], m1 = mxB[t], s0 = smA[t], s1 = smB[t];
#pragma unroll
    for (int qq = 1; qq < 4; ++qq) {
      m0 = fmaxf(m0, mxA[qq * 64 + t]); m1 = fmaxf(m1, mxB[qq * 64 + t]);
      s0 += smA[qq * 64 + t];           s1 += smB[qq * 64 + t];
    }
    float* o = xlp + (size_t)blk * 256;
    o[2 * t]           = m0;
    o[2 * t + 1]       = m1;
    o[128 + 2 * t]     = s0;
    o[128 + 2 * t + 1] = s1;
  }
}

// ---------------- Final MLP head, one block per graph ----------------
__global__ __launch_bounds__(256) void mlp_k(
    const float* __restrict__ xlp,
    const float* __restrict__ W1, const float* __restrict__ b1,
    const float* __restrict__ W2, const float* __restrict__ b2,
    const float* __restrict__ W3, const float* __restrict__ b3,
    float* __restrict__ out)
{
  __shared__ float h0[256];
  __shared__ float h1[128];
  __shared__ float h2[64];
  const int b = blockIdx.x, t = threadIdx.x;
  const float invK[3] = {1.0f / (float)K1, 1.0f / (float)K2, 1.0f / (float)K3};
  float v = 0.0f;
#pragma unroll
  for (int l = 0; l < 3; ++l) {
    const float* base = xlp + ((size_t)l * NB * 8 + (size_t)b * 8) * 256;
    if (t < 128) {
      float m = base[t];
#pragma unroll
      for (int pr = 1; pr < 8; ++pr) m = fmaxf(m, base[pr * 256 + t]);
      v += m;
    } else {
      float s = 0.0f;
#pragma unroll
      for (int pr = 0; pr < 8; ++pr) s += base[pr * 256 + t];
      v += s * invK[l];
    }
  }
  h0[t] = v;
  __syncthreads();
  if (t < 128) {
    float a = b1[t];
    for (int k = 0; k < 256; ++k) a += h0[k] * W1[k * 128 + t];
    h1[t] = fmaxf(a, 0.0f);
  }
  __syncthreads();
  if (t < 64) {
    float a = b2[t];
    for (int k = 0; k < 128; ++k) a += h1[k] * W2[k * 64 + t];
    h2[t] = fmaxf(a, 0.0f);
  }
  __syncthreads();
  if (t < 64) {
    float vv = h2[t] * W3[t];
#pragma unroll
    for (int off = 32; off > 0; off >>= 1) vv += __shfl_xor(vv, off, 64);
    if (t == 0) out[b] = 1.0f / (1.0f + expf(-(vv + b3[0])));
  }
}

extern "C" void kernel_launch(void* const* d_in, const int* in_sizes, int n_in,
                              void* d_out, int out_size, void* d_ws, size_t ws_size,
                              hipStream_t stream)
{
  const int*   x_ids = (const int*)d_in[0];
  const int*   ei    = (const int*)d_in[1];
  const float* emb   = (const float*)d_in[3];
  const float* Wl[3]  = {(const float*)d_in[4],  (const float*)d_in[8],  (const float*)d_in[12]};
  const float* blv[3] = {(const float*)d_in[5],  (const float*)d_in[9],  (const float*)d_in[13]};
  const float* Wr[3]  = {(const float*)d_in[6],  (const float*)d_in[10], (const float*)d_in[14]};
  const float* pv[3]  = {(const float*)d_in[7],  (const float*)d_in[11], (const float*)d_in[15]};
  const float* W1 = (const float*)d_in[16]; const float* b1 = (const float*)d_in[17];
  const float* W2 = (const float*)d_in[18]; const float* b2 = (const float*)d_in[19];
  const float* W3 = (const float*)d_in[20]; const float* b3 = (const float*)d_in[21];

  char* ws = (char*)d_ws;
  size_t off = 0;
  auto alloc = [&](size_t bytes) -> void* {
    void* ptr = ws + off; off += (bytes + 255) & ~(size_t)255; return ptr;
  };
  u16*   xA    = (u16*)  alloc((size_t)NNODES * DF * 2);   // feature ping
  u16*   xB    = (u16*)  alloc((size_t)NNODES * DF * 2);   // agg buffer
  float* score = (float*)alloc((size_t)NNODES * 4);
  float* keep  = (float*)alloc((size_t)NNODES * 4);
  float* fac   = (float*)alloc((size_t)NNODES * 4);
  float* degf  = (float*)alloc((size_t)NNODES * 4);
  int*   csr   = (int*)  alloc((size_t)NEDGE * 4);
  int*   roff  = (int*)  alloc((size_t)NNODES * 4);
  int*   rcnt  = (int*)  alloc((size_t)NNODES * 4);
  int*   perm  = (int*)  alloc((size_t)NNODES * 4);
  u16*   wF    = (u16*)  alloc((size_t)3 * 64 * 64 * 8 * 2);
  float* xlp   = (float*)alloc((size_t)3 * NB * 8 * 256 * 4);  // readout partials
  const size_t off_base = off;
  u16*   xC    = (u16*)  alloc((size_t)NNODES * DF * 2);   // feature pong
  const bool use3 = (off <= ws_size);
  (void)in_sizes; (void)n_in; (void)out_size;
  if (off_base > ws_size) return;   // graceful fail instead of OOB fault
  if (!use3) return;                // requires the 3rd buffer (has fit so far)

  wcvt_k<<<192, 64, 0, stream>>>(Wl[0], Wr[0], Wl[1], Wr[1], Wl[2], Wr[2], wF);
  build_csr_k<<<NB, 1024, 0, stream>>>(ei, csr, roff, rcnt, degf, keep, perm);
  gather_k<<<NNODES * 16 / 256, 256, 0, stream>>>(x_ids, emb, xA, fac);
  const int Ks[3] = {K1, K2, K3};
  u16* F = xA;
  u16* H = xC;
  for (int l = 0; l < 3; ++l) {
    agg_k<<<1024, 1024, 0, stream>>>(F, fac, degf, csr, roff, rcnt, perm, xB);
    gemm_nb_k<<<1024, 512, 0, stream>>>(xB, F, fac, wF + (size_t)l * 32768,
                                        blv[l], pv[l], H, score);
    rank_k<<<NB, 1024, 0, stream>>>(score, pv[l], ei, keep, fac, degf,
                                    Ks[l], l < 2 ? 1 : 0);
    readout_k<<<NB * 8, 256, 0, stream>>>(H, fac, keep,
                                          xlp + (size_t)l * NB * 8 * 256);
    u16* tmp = F; F = H; H = tmp;   // xn (in F now) is next layer's features
  }
  mlp_k<<<NB, 256, 0, stream>>>(xlp, W1, b1, W2, b2, W3, b3, (float*)d_out);
}

// Round 11
// 596.053 us; speedup vs baseline: 1.3470x; 1.3470x over previous
//
#include <hip/hip_runtime.h>
#include <math.h>

#define NNODES 262144      // B*N
#define NEDGE  2097152     // NNODES*DEG
#define NB     256         // graphs
#define NPG    1024        // nodes per graph
#define EPG    8192        // edges per graph
#define DF     128         // feature dim

typedef unsigned short u16;
typedef unsigned int   u32;
typedef unsigned long long u64;
typedef __attribute__((ext_vector_type(8))) short  short8;   // 8 x bf16 (4 VGPRs)
typedef __attribute__((ext_vector_type(4))) float  floatx4;  // MFMA accumulator

static constexpr int K1 = 820, K2 = 656, K3 = 525;

// ---- bf16 helpers (manual, RTNE) ----
__device__ inline float bflo(u32 u) { union { u32 i; float f; } c; c.i = u << 16;          return c.f; }
__device__ inline float bfhi(u32 u) { union { u32 i; float f; } c; c.i = u & 0xffff0000u;  return c.f; }
__device__ inline u32   f2bf(float f) {
  union { float f; u32 i; } c; c.f = f;
  const u32 r = c.i + 0x7fffu + ((c.i >> 16) & 1u);
  return r >> 16;
}
__device__ inline void acc8(float* b, uint4 v) {
  b[0] += bflo(v.x); b[1] += bfhi(v.x);
  b[2] += bflo(v.y); b[3] += bfhi(v.y);
  b[4] += bflo(v.z); b[5] += bfhi(v.z);
  b[6] += bflo(v.w); b[7] += bfhi(v.w);
}
__device__ inline uint4 pack8(const float* s, float k) {
  uint4 o;
  o.x = f2bf(s[0] * k) | (f2bf(s[1] * k) << 16);
  o.y = f2bf(s[2] * k) | (f2bf(s[3] * k) << 16);
  o.z = f2bf(s[4] * k) | (f2bf(s[5] * k) << 16);
  o.w = f2bf(s[6] * k) | (f2bf(s[7] * k) << 16);
  return o;
}

// ---------------- CSR build (1024 thr): counting sort by dst + deg/keep init ----
__global__ __launch_bounds__(1024) void build_csr_k(
    const int* __restrict__ ei, int* __restrict__ csr_src,
    int* __restrict__ row_off, int* __restrict__ row_cnt,
    float* __restrict__ degf, float* __restrict__ keep,
    int* __restrict__ perm)
{
  __shared__ int cnt[NPG];
  __shared__ int roff[NPG];
  __shared__ int wsum[NPG];
  __shared__ int hist[64];
  __shared__ int hoff[64];
  const int b = blockIdx.x, t = threadIdx.x;   // t in 0..1023
  const int* src = ei;
  const int* dst = ei + NEDGE;
  const int e0 = b * EPG;
  cnt[t] = 0;
  __syncthreads();
  for (int e = t; e < EPG; e += 1024) atomicAdd(&cnt[dst[e0 + e] & (NPG - 1)], 1);
  __syncthreads();
  const int v = cnt[t];
  wsum[t] = v;
  __syncthreads();
  for (int off = 1; off < NPG; off <<= 1) {
    const int u = (t >= off) ? wsum[t - off] : 0;
    __syncthreads();
    wsum[t] += u;
    __syncthreads();
  }
  const int base = wsum[t] - v;    // exclusive prefix
  roff[t] = base;
  const int n = b * NPG + t;
  row_off[n] = base;
  row_cnt[n] = v;
  degf[n]    = (float)v;           // layer-1 deg = full in-degree
  keep[n]    = 1.0f;
  if (t < 64) hist[t] = 0;
  __syncthreads();
  for (int e = t; e < EPG; e += 1024) {
    const int dl = dst[e0 + e] & (NPG - 1);
    const int pos = atomicAdd(&roff[dl], 1);
    csr_src[e0 + pos] = src[e0 + e];   // store GLOBAL src node id
  }
  // ---- degree-sorted permutation (counting sort over clamped degree) ----
  const int bkt = (v < 63) ? v : 63;
  atomicAdd(&hist[bkt], 1);
  __syncthreads();
  if (t == 0) {
    int s = 0;
#pragma unroll 1
    for (int i = 0; i < 64; ++i) { const int h = hist[i]; hoff[i] = s; s += h; }
  }
  __syncthreads();
  const int pp = atomicAdd(&hoff[bkt], 1);
  perm[b * NPG + pp] = t;
}

// ---------------- Embedding gather (f32 -> bf16, unscaled) + fac init -----------
__global__ __launch_bounds__(256) void gather_k(
    const int* __restrict__ x_ids, const float* __restrict__ emb,
    u16* __restrict__ x0, float* __restrict__ fac)
{
  const int gid = blockIdx.x * 256 + threadIdx.x;  // NNODES*16 threads
  const int n = gid >> 4, c = gid & 15;
  const int id = x_ids[n];
  const float4 v0 = *(const float4*)(emb + (size_t)id * DF + c * 8);
  const float4 v1 = *(const float4*)(emb + (size_t)id * DF + c * 8 + 4);
  uint4 pk;
  pk.x = f2bf(v0.x) | (f2bf(v0.y) << 16);
  pk.y = f2bf(v0.z) | (f2bf(v0.w) << 16);
  pk.z = f2bf(v1.x) | (f2bf(v1.y) << 16);
  pk.w = f2bf(v1.z) | (f2bf(v1.w) << 16);
  *(uint4*)(x0 + (size_t)n * DF + c * 8) = pk;
  if (c == 0) fac[n] = 1.0f;
}

// ---- Weight convert into SWIZZLED fragment order -------------------------------
__global__ __launch_bounds__(64) void wcvt_k(
    const float* __restrict__ Wl1, const float* __restrict__ Wr1,
    const float* __restrict__ Wl2, const float* __restrict__ Wr2,
    const float* __restrict__ Wl3, const float* __restrict__ Wr3,
    u16* __restrict__ wF)
{
  const int f = blockIdx.x & 63, l = blockIdx.x >> 6;
  const int lane = threadIdx.x;
  const int ct = f >> 3, ks = f & 7;
  const int n = ct * 16 + (lane & 15);
  const int k0 = ks * 32 + (lane >> 4) * 8;
  const float* Wl = (l == 0) ? Wl1 : (l == 1) ? Wl2 : Wl3;
  const float* Wr = (l == 0) ? Wr1 : (l == 1) ? Wr2 : Wr3;
  u16 o[8];
#pragma unroll
  for (int j = 0; j < 8; ++j) {
    const int k = k0 + j;
    const float v = (k < 128) ? Wl[k * 128 + n] : Wr[(k - 128) * 128 + n];
    o[j] = (u16)f2bf(v);
  }
  uint4 pk;
  pk.x = (u32)o[0] | ((u32)o[1] << 16);
  pk.y = (u32)o[2] | ((u32)o[3] << 16);
  pk.z = (u32)o[4] | ((u32)o[5] << 16);
  pk.w = (u32)o[6] | ((u32)o[7] << 16);
  *(uint4*)(wF + (((size_t)l * 64 + f) * 64 + lane) * 8) = pk;
}

// ---- Aggregation v10: clean structure + 8-group swizzle ------------------------
__global__ __launch_bounds__(1024) void agg_k(
    const u16* __restrict__ xprev, const float* __restrict__ fac,
    const float* __restrict__ deg,
    const int* __restrict__ csr_src, const int* __restrict__ row_off,
    const int* __restrict__ row_cnt, const int* __restrict__ perm,
    u16* __restrict__ aggb)
{
  __shared__ u32 xl[16384];          // 64 KB: 1024 rows x 16 dwords (32 bf16)
  const int t = threadIdx.x;
  const int bi = blockIdx.x;         // 1024 = 256 graphs x 4 quarters
  const int g  = (bi & 7) + 8 * (bi >> 5);     // XCD swizzle
  const int qt = (bi >> 3) & 3;
  const int n  = g * NPG + t;
  // ---- stage (scaled; 8-group swizzle: group = 4*(r&1) + ((r>>1)&3)) ----
  {
    const float fr = fac[n];
    const uint4* src = (const uint4*)(xprev + (size_t)n * DF + qt * 32);
    u32* dst = xl + t * 16;
    const int sw = ((t >> 1) & 3) << 2;
#pragma unroll
    for (int j = 0; j < 4; ++j) {
      const uint4 v = src[j];
      uint4 o;
      o.x = f2bf(bflo(v.x) * fr) | (f2bf(bfhi(v.x) * fr) << 16);
      o.y = f2bf(bflo(v.y) * fr) | (f2bf(bfhi(v.y) * fr) << 16);
      o.z = f2bf(bflo(v.z) * fr) | (f2bf(bfhi(v.z) * fr) << 16);
      o.w = f2bf(bflo(v.w) * fr) | (f2bf(bfhi(v.w) * fr) << 16);
      *(uint4*)(dst + ((j << 2) ^ sw)) = o;
    }
  }
  const int m  = perm[n];            // node this thread aggregates
  const int nm = g * NPG + m;
  __syncthreads();
  // ---- gather-sum from LDS (pairwise) ----
  const int cnt = row_cnt[nm];
  const int* ep = csr_src + g * EPG + row_off[nm];
  float b[32];
#pragma unroll
  for (int j = 0; j < 32; ++j) b[j] = 0.0f;
  int e = 0;
  for (; e + 2 <= cnt; e += 2) {
    const int s0 = ep[e] & (NPG - 1), s1 = ep[e + 1] & (NPG - 1);
    const u32* r0 = xl + s0 * 16; const int w0 = ((s0 >> 1) & 3) << 2;
    const u32* r1 = xl + s1 * 16; const int w1 = ((s1 >> 1) & 3) << 2;
    const uint4 A0 = *(const uint4*)(r0 + (0  ^ w0));
    const uint4 A1 = *(const uint4*)(r0 + (4  ^ w0));
    const uint4 A2 = *(const uint4*)(r0 + (8  ^ w0));
    const uint4 A3 = *(const uint4*)(r0 + (12 ^ w0));
    const uint4 B0 = *(const uint4*)(r1 + (0  ^ w1));
    const uint4 B1 = *(const uint4*)(r1 + (4  ^ w1));
    const uint4 B2 = *(const uint4*)(r1 + (8  ^ w1));
    const uint4 B3 = *(const uint4*)(r1 + (12 ^ w1));
    acc8(b + 0, A0); acc8(b + 8, A1); acc8(b + 16, A2); acc8(b + 24, A3);
    acc8(b + 0, B0); acc8(b + 8, B1); acc8(b + 16, B2); acc8(b + 24, B3);
  }
  if (e < cnt) {
    const int s0 = ep[e] & (NPG - 1);
    const u32* r0 = xl + s0 * 16; const int w0 = ((s0 >> 1) & 3) << 2;
    const uint4 A0 = *(const uint4*)(r0 + (0  ^ w0));
    const uint4 A1 = *(const uint4*)(r0 + (4  ^ w0));
    const uint4 A2 = *(const uint4*)(r0 + (8  ^ w0));
    const uint4 A3 = *(const uint4*)(r0 + (12 ^ w0));
    acc8(b + 0, A0); acc8(b + 8, A1); acc8(b + 16, A2); acc8(b + 24, A3);
  }
  const float inv = 1.0f / fmaxf(deg[nm], 1.0f);
  uint4* op = (uint4*)(aggb + (size_t)nm * DF + qt * 32);
  op[0] = pack8(b + 0,  inv);
  op[1] = pack8(b + 8,  inv);
  op[2] = pack8(b + 16, inv);
  op[3] = pack8(b + 24, inv);
}

// ---- MFMA GEMM v6: weights in LDS (frees 128 VGPRs), barrier-free main loop ----
__global__ __launch_bounds__(512) void gemm_nb_k(
    const u16* __restrict__ G, const u16* __restrict__ F,
    const float* __restrict__ fac,
    const u16* __restrict__ wF, const float* __restrict__ bl,
    const float* __restrict__ p, u16* __restrict__ H,
    float* __restrict__ score)
{
  __shared__ uint4 wL[4096];           // 64 KB: fragment (f,lane) -> uint4
  __shared__ float sc[256][2];
  const int t = threadIdx.x;
  const int bi = blockIdx.x;           // 1024 = 256 graphs x 4
  const int g   = (bi & 7) + 8 * (bi >> 5);
  const int tpg = (bi >> 3) & 3;
  const int n0  = g * NPG + tpg * 256;
  const int wv = t >> 6, lane = t & 63;
  const int rg = wv >> 1, ch = wv & 1;
  const int lr = lane & 15, quad = lane >> 4;

  // ---- stage layer weights into LDS (once per block) ----
  {
    const uint4* ws = (const uint4*)wF;
#pragma unroll
    for (int c = 0; c < 8; ++c) wL[t + c * 512] = ws[t + c * 512];
  }
  float4 bn4[4], pn4[4];
#pragma unroll
  for (int ct = 0; ct < 4; ++ct) {
    const int fb = ch * 64 + ct * 16 + quad * 4;
    bn4[ct] = *(const float4*)(bl + fb);
    pn4[ct] = *(const float4*)(p + fb);
  }

  const int rb0 = n0 + rg * 64 + lr;
  short8 agc[4], axc[4], agn[4], axn[4];
  float frc, frn = 0.0f;
#pragma unroll
  for (int ks = 0; ks < 4; ++ks) {
    agn[ks] = (short8)(short)0;
    axn[ks] = (short8)(short)0;
    agc[ks] = *(const short8*)(G + (size_t)rb0 * DF + ks * 32 + quad * 8);
    axc[ks] = *(const short8*)(F + (size_t)rb0 * DF + ks * 32 + quad * 8);
  }
  frc = fac[rb0];
  __syncthreads();                     // weights staged

  const short8* wLs = (const short8*)wL;   // fragment f at wLs[f*64+lane]
#pragma unroll
  for (int tl = 0; tl < 4; ++tl) {
    const int row = rb0 + tl * 16;
    if (tl < 3) {
      const int rown = row + 16;
#pragma unroll
      for (int ks = 0; ks < 4; ++ks) {
        agn[ks] = *(const short8*)(G + (size_t)rown * DF + ks * 32 + quad * 8);
        axn[ks] = *(const short8*)(F + (size_t)rown * DF + ks * 32 + quad * 8);
      }
      frn = fac[rown];
    }
    floatx4 aL[4], aR[4];
#pragma unroll
    for (int ct = 0; ct < 4; ++ct) {
      aL[ct] = (floatx4){0.f, 0.f, 0.f, 0.f};
      aR[ct] = (floatx4){0.f, 0.f, 0.f, 0.f};
    }
#pragma unroll
    for (int ks = 0; ks < 4; ++ks)
#pragma unroll
      for (int ct = 0; ct < 4; ++ct) {
        const int f = (ch * 4 + ct) * 8;
        const short8 bfa = wLs[(size_t)(f + ks) * 64 + lane];
        const short8 bfb = wLs[(size_t)(f + ks + 4) * 64 + lane];
        aL[ct] = __builtin_amdgcn_mfma_f32_16x16x32_bf16(bfa, agc[ks], aL[ct], 0, 0, 0);
        aR[ct] = __builtin_amdgcn_mfma_f32_16x16x32_bf16(bfb, axc[ks], aR[ct], 0, 0, 0);
      }
    float si = 0.0f;
#pragma unroll
    for (int ct = 0; ct < 4; ++ct) {
      float v0 = fmaxf(aL[ct][0] + frc * aR[ct][0] + bn4[ct].x, 0.0f);
      float v1 = fmaxf(aL[ct][1] + frc * aR[ct][1] + bn4[ct].y, 0.0f);
      float v2 = fmaxf(aL[ct][2] + frc * aR[ct][2] + bn4[ct].z, 0.0f);
      float v3 = fmaxf(aL[ct][3] + frc * aR[ct][3] + bn4[ct].w, 0.0f);
      si += v0 * pn4[ct].x + v1 * pn4[ct].y + v2 * pn4[ct].z + v3 * pn4[ct].w;
      uint2 st;
      st.x = f2bf(v0) | (f2bf(v1) << 16);
      st.y = f2bf(v2) | (f2bf(v3) << 16);
      *(uint2*)(H + (size_t)row * DF + ch * 64 + ct * 16 + quad * 4) = st;
    }
    si += __shfl_xor(si, 16, 64);
    si += __shfl_xor(si, 32, 64);
    if (lane < 16) sc[rg * 64 + tl * 16 + lr][ch] = si;
#pragma unroll
    for (int ks = 0; ks < 4; ++ks) { agc[ks] = agn[ks]; axc[ks] = axn[ks]; }
    frc = frn;
  }
  __syncthreads();   // sc complete across ch pair
  if (t < 256) score[n0 + t] = sc[t][0] + sc[t][1];
}

// ---- rank v4: radix-select with PARALLEL suffix-scan bin selection -------------
// R10's t==0 serial 256-bin scan (control-dep ds_read chain, ~50us across 4
// passes, VALUBusy 3.8%) replaced by: 256 threads load hist, intra-wave suffix
// scan via shfl_down (6 steps), 4 wave totals via LDS; selected bin satisfies
// S[t]>=Kr && S[t]-h[t]<Kr (unique since S strictly decreasing where h>0).
__global__ __launch_bounds__(1024) void rank_k(
    const float* __restrict__ score, const float* __restrict__ p,
    const int* __restrict__ ei,
    float* __restrict__ keep, float* __restrict__ fac,
    float* __restrict__ degN, int K, int next)
{
  __shared__ int hist[256];
  __shared__ int wsum4[4];
  __shared__ int hsel[2];            // [bin, cumAbove]
  __shared__ int wtie[16];
  __shared__ float kfl[NPG];
  __shared__ float deg_l[NPG];
  const int b = blockIdx.x, t = threadIdx.x;
  const int lane = t & 63, wv = t >> 6;
  float ssq = 0.0f;
  for (int d = 0; d < DF; ++d) ssq += p[d] * p[d];
  const float inv_pn = 1.0f / sqrtf(ssq);
  const int n = b * NPG + t;
  const float sc = score[n];
  const bool act = keep[n] > 0.5f;
  u32 u;
  {
    union { float f; u32 i; } c; c.f = sc;
    u = (c.i & 0x80000000u) ? ~c.i : (c.i | 0x80000000u);
    if (!act) u = 0u;                // strictly below every active mapping
  }
  deg_l[t] = 0.0f;
  // ---- 4-pass radix select for the K-th largest u ----
  u32 prefix = 0, pmask = 0;
  int Kr = K;
#pragma unroll 1
  for (int pass = 0; pass < 4; ++pass) {
    const int shift = 24 - pass * 8;
    if (t < 256) hist[t] = 0;
    __syncthreads();
    if ((u & pmask) == prefix) atomicAdd(&hist[(u >> shift) & 255], 1);
    __syncthreads();
    int h = 0, S = 0;
    if (t < 256) { h = hist[t]; S = h; }
    // intra-wave suffix scan (S = sum of h over lanes >= lane, within wave)
#pragma unroll
    for (int off = 1; off < 64; off <<= 1) {
      const int v2 = __shfl_down(S, off, 64);
      if (lane + off < 64) S += v2;
    }
    if (t < 256 && lane == 0) wsum4[wv] = S;   // wave totals (wv in 0..3)
    __syncthreads();
    if (t < 256) {
      int add = 0;
#pragma unroll
      for (int w = 0; w < 4; ++w) add += (w > wv) ? wsum4[w] : 0;
      S += add;                        // global suffix sum over bins >= t
      const int cumAbove = S - h;      // count in bins strictly above t
      if (S >= Kr && cumAbove < Kr) { hsel[0] = t; hsel[1] = cumAbove; }
    }
    __syncthreads();
    prefix |= ((u32)hsel[0]) << shift;
    pmask  |= 0xFFu << shift;
    Kr     -= hsel[1];
  }
  // ---- tie index (count of tied nodes with smaller t) ----
  const bool tie = (u == prefix);
  const u64 mb = __ballot(tie);
  const int tl = __popcll(mb & ((1ULL << lane) - 1ULL));
  if (lane == 0) wtie[wv] = (int)__popcll(mb);
  __syncthreads();
  int tsum = 0;
#pragma unroll
  for (int w = 0; w < 16; ++w) tsum += (w < wv) ? wtie[w] : 0;
  const bool kp = (u > prefix) || (tie && (tsum + tl) < Kr);
  const float fv = kp ? tanhf(sc * inv_pn) : 0.0f;
  keep[n] = kp ? 1.0f : 0.0f;
  fac[n]  = fv;
  kfl[t]  = kp ? 1.0f : 0.0f;
  __syncthreads();
  if (next) {
    const int e0 = b * EPG;
    for (int e = t; e < EPG; e += 1024) {
      const int sl = ei[e0 + e] & (NPG - 1);
      const int dl = ei[NEDGE + e0 + e] & (NPG - 1);
      atomicAdd(&deg_l[dl], kfl[sl]);
    }
    __syncthreads();
    degN[n] = deg_l[t];
  }
}

// ---- Parallel masked readout v2: 8 blocks/graph, uint2 loads, LDS keep/fac ----
// Standalone (fusion into agg/rank measured +19/+36us). v2: keep/fac staged to
// LDS once per row (was re-loaded from global every j-iter), uint2 feature
// loads (4 bf16, was 2) -> 1 global load/iter instead of 3, 16 iters not 32.
__global__ __launch_bounds__(256) void readout_k(
    const u16* __restrict__ xn, const float* __restrict__ fac,
    const float* __restrict__ keep, float* __restrict__ xlp)
{
  __shared__ float fL[128], kL[128];
  __shared__ float mxL[8][128];
  __shared__ float smL[8][128];
  const int blk = blockIdx.x, b = blk >> 3, pr = blk & 7, t = threadIdx.x;
  const int d2 = t & 31, rq = t >> 5;     // uint2 chunk (4 dims), row-group 0..7
  const int r0 = pr * 128;
  if (t < 128) {
    const int n = b * NPG + r0 + t;
    kL[t] = keep[n];
    fL[t] = fac[n];
  }
  __syncthreads();
  const float NEG = -__builtin_huge_valf();
  float mx0 = NEG, mx1 = NEG, mx2 = NEG, mx3 = NEG;
  float s0 = 0.f, s1 = 0.f, s2 = 0.f, s3 = 0.f;
  const u16* base = xn + (size_t)(b * NPG + r0) * DF;
#pragma unroll 4
  for (int j = 0; j < 16; ++j) {
    const int r = rq + j * 8;
    if (kL[r] > 0.5f) {
      const uint2 v = *(const uint2*)(base + (size_t)r * DF + d2 * 4);
      const float f = fL[r];
      const float a0 = bflo(v.x) * f, a1 = bfhi(v.x) * f;
      const float a2 = bflo(v.y) * f, a3 = bfhi(v.y) * f;
      mx0 = fmaxf(mx0, a0); mx1 = fmaxf(mx1, a1);
      mx2 = fmaxf(mx2, a2); mx3 = fmaxf(mx3, a3);
      s0 += a0; s1 += a1; s2 += a2; s3 += a3;
    }
  }
  mxL[rq][d2 * 4 + 0] = mx0; mxL[rq][d2 * 4 + 1] = mx1;
  mxL[rq][d2 * 4 + 2] = mx2; mxL[rq][d2 * 4 + 3] = mx3;
  smL[rq][d2 * 4 + 0] = s0;  smL[rq][d2 * 4 + 1] = s1;
  smL[rq][d2 * 4 + 2] = s2;  smL[rq][d2 * 4 + 3] = s3;
  __syncthreads();
  if (t < 128) {
    float m = mxL[0][t], s = smL[0][t];
#pragma unroll
    for (int w = 1; w < 8; ++w) {
      m = fmaxf(m, mxL[w][t]);
      s += smL[w][t];
    }
    float* o = xlp + (size_t)blk * 256;
    o[t]       = m;
    o[128 + t] = s;
  }
}

// ---------------- Final MLP head, one block per graph ----------------
__global__ __launch_bounds__(256) void mlp_k(
    const float* __restrict__ xlp,
    const float* __restrict__ W1, const float* __restrict__ b1,
    const float* __restrict__ W2, const float* __restrict__ b2,
    const float* __restrict__ W3, const float* __restrict__ b3,
    float* __restrict__ out)
{
  __shared__ float h0[256];
  __shared__ float h1[128];
  __shared__ float h2[64];
  const int b = blockIdx.x, t = threadIdx.x;
  const float invK[3] = {1.0f / (float)K1, 1.0f / (float)K2, 1.0f / (float)K3};
  float v = 0.0f;
#pragma unroll
  for (int l = 0; l < 3; ++l) {
    const float* base = xlp + ((size_t)l * NB * 8 + (size_t)b * 8) * 256;
    if (t < 128) {
      float m = base[t];
#pragma unroll
      for (int pr = 1; pr < 8; ++pr) m = fmaxf(m, base[pr * 256 + t]);
      v += m;
    } else {
      float s = 0.0f;
#pragma unroll
      for (int pr = 0; pr < 8; ++pr) s += base[pr * 256 + t];
      v += s * invK[l];
    }
  }
  h0[t] = v;
  __syncthreads();
  if (t < 128) {
    float a = b1[t];
    for (int k = 0; k < 256; ++k) a += h0[k] * W1[k * 128 + t];
    h1[t] = fmaxf(a, 0.0f);
  }
  __syncthreads();
  if (t < 64) {
    float a = b2[t];
    for (int k = 0; k < 128; ++k) a += h1[k] * W2[k * 64 + t];
    h2[t] = fmaxf(a, 0.0f);
  }
  __syncthreads();
  if (t < 64) {
    float vv = h2[t] * W3[t];
#pragma unroll
    for (int off = 32; off > 0; off >>= 1) vv += __shfl_xor(vv, off, 64);
    if (t == 0) out[b] = 1.0f / (1.0f + expf(-(vv + b3[0])));
  }
}

extern "C" void kernel_launch(void* const* d_in, const int* in_sizes, int n_in,
                              void* d_out, int out_size, void* d_ws, size_t ws_size,
                              hipStream_t stream)
{
  const int*   x_ids = (const int*)d_in[0];
  const int*   ei    = (const int*)d_in[1];
  const float* emb   = (const float*)d_in[3];
  const float* Wl[3]  = {(const float*)d_in[4],  (const float*)d_in[8],  (const float*)d_in[12]};
  const float* blv[3] = {(const float*)d_in[5],  (const float*)d_in[9],  (const float*)d_in[13]};
  const float* Wr[3]  = {(const float*)d_in[6],  (const float*)d_in[10], (const float*)d_in[14]};
  const float* pv[3]  = {(const float*)d_in[7],  (const float*)d_in[11], (const float*)d_in[15]};
  const float* W1 = (const float*)d_in[16]; const float* b1 = (const float*)d_in[17];
  const float* W2 = (const float*)d_in[18]; const float* b2 = (const float*)d_in[19];
  const float* W3 = (const float*)d_in[20]; const float* b3 = (const float*)d_in[21];

  char* ws = (char*)d_ws;
  size_t off = 0;
  auto alloc = [&](size_t bytes) -> void* {
    void* ptr = ws + off; off += (bytes + 255) & ~(size_t)255; return ptr;
  };
  u16*   xA    = (u16*)  alloc((size_t)NNODES * DF * 2);   // feature ping
  u16*   xB    = (u16*)  alloc((size_t)NNODES * DF * 2);   // agg buffer
  float* score = (float*)alloc((size_t)NNODES * 4);
  float* keep  = (float*)alloc((size_t)NNODES * 4);
  float* fac   = (float*)alloc((size_t)NNODES * 4);
  float* degf  = (float*)alloc((size_t)NNODES * 4);
  int*   csr   = (int*)  alloc((size_t)NEDGE * 4);
  int*   roff  = (int*)  alloc((size_t)NNODES * 4);
  int*   rcnt  = (int*)  alloc((size_t)NNODES * 4);
  int*   perm  = (int*)  alloc((size_t)NNODES * 4);
  u16*   wF    = (u16*)  alloc((size_t)3 * 64 * 64 * 8 * 2);
  float* xlp   = (float*)alloc((size_t)3 * NB * 8 * 256 * 4);  // readout partials
  const size_t off_base = off;
  u16*   xC    = (u16*)  alloc((size_t)NNODES * DF * 2);   // feature pong
  const bool use3 = (off <= ws_size);
  (void)in_sizes; (void)n_in; (void)out_size;
  if (off_base > ws_size) return;   // graceful fail instead of OOB fault
  if (!use3) return;                // requires the 3rd buffer (has fit so far)

  wcvt_k<<<192, 64, 0, stream>>>(Wl[0], Wr[0], Wl[1], Wr[1], Wl[2], Wr[2], wF);
  build_csr_k<<<NB, 1024, 0, stream>>>(ei, csr, roff, rcnt, degf, keep, perm);
  gather_k<<<NNODES * 16 / 256, 256, 0, stream>>>(x_ids, emb, xA, fac);
  const int Ks[3] = {K1, K2, K3};
  u16* F = xA;
  u16* H = xC;
  for (int l = 0; l < 3; ++l) {
    agg_k<<<1024, 1024, 0, stream>>>(F, fac, degf, csr, roff, rcnt, perm, xB);
    gemm_nb_k<<<1024, 512, 0, stream>>>(xB, F, fac, wF + (size_t)l * 32768,
                                        blv[l], pv[l], H, score);
    rank_k<<<NB, 1024, 0, stream>>>(score, pv[l], ei, keep, fac, degf,
                                    Ks[l], l < 2 ? 1 : 0);
    readout_k<<<NB * 8, 256, 0, stream>>>(H, fac, keep,
                                          xlp + (size_t)l * NB * 8 * 256);
    u16* tmp = F; F = H; H = tmp;   // xn (in F now) is next layer's features
  }
  mlp_k<<<NB, 256, 0, stream>>>(xlp, W1, b1, W2, b2, W3, b3, (float*)d_out);
}